// Round 1
// 5331.241 us; speedup vs baseline: 1.7530x; 1.7530x over previous
//
#include <hip/hip_runtime.h>
#include <math.h>

// ---------------- problem constants ----------------
constexpr int Bc  = 256;   // batch
constexpr int Tc  = 64;    // time
constexpr int Ac  = 64;    // action dim
constexpr int Ec  = 1024;  // obs embed
constexpr int HIDc = 1024;
constexpr int DETc = 2048;
constexpr int STOc = 256;

typedef __attribute__((ext_vector_type(8))) short  s8v;
typedef __attribute__((ext_vector_type(8))) float  f8v;
typedef __attribute__((ext_vector_type(8))) __bf16 bf8v;
typedef __attribute__((ext_vector_type(4))) float  f4v;

__device__ inline unsigned short f2bf(float f) {
  union { float f; unsigned u; } v; v.f = f;
  return (unsigned short)((v.u + 0x7FFF + ((v.u >> 16) & 1)) >> 16); // RNE
}
__device__ inline float bf2f(unsigned short u) {
  union { unsigned u; float f; } v; v.u = (unsigned)u << 16; return v.f;
}
__device__ inline float sigm(float x) { return 1.0f / (1.0f + expf(-x)); }
__device__ inline float softplusf(float x) {
  return fmaxf(x, 0.0f) + log1pf(expf(-fabsf(x)));
}
__device__ inline f4v mfma16(bf8v a, bf8v b, f4v c) {
  return __builtin_amdgcn_mfma_f32_16x16x32_bf16(a, b, c, 0, 0, 0);
}

// ---------------- precompute kernels ----------------
__global__ void k_cvt(const float* __restrict__ in, unsigned short* __restrict__ out, int n) {
  int i = blockIdx.x * 256 + threadIdx.x;
  if (i < n) out[i] = f2bf(in[i]);
}
// out[n*opitch + k] = bf16(in[k*ipitch + n])
__global__ void k_tr(const float* __restrict__ in, int ipitch,
                     unsigned short* __restrict__ out, int opitch, int N, int K) {
  int k = blockIdx.x * 16 + (threadIdx.x & 15);
  int n = blockIdx.y * 16 + (threadIdx.x >> 4);
  if (k < K && n < N) out[n * opitch + k] = f2bf(in[k * ipitch + n]);
}
// a_shift[t][b][j] = (t==0) ? 0 : bf16(actions[b][t-1][j])
__global__ void k_ashift(const float* __restrict__ actions, unsigned short* __restrict__ out) {
  int i = blockIdx.x * 256 + threadIdx.x;
  if (i >= Tc * Bc * Ac) return;
  int j = i & 63, b = (i >> 6) & 255, t = i >> 14;
  out[i] = (t == 0) ? (unsigned short)0 : f2bf(actions[(b * Tc + (t - 1)) * Ac + j]);
}
__global__ void k_zero16(unsigned short* p, int n) {
  int i = blockIdx.x * 256 + threadIdx.x;
  if (i < n) p[i] = 0;
}

// ---------------- batched: Oc = obs @ Wobs + b_post_in (NO relu), row r = t*256+b ----------
__global__ __launch_bounds__(256) void k_obs(
    const float* __restrict__ obs, const unsigned short* __restrict__ Wobs_t,
    const float* __restrict__ b_post_in, unsigned short* __restrict__ Oc) {
  __shared__ __align__(16) short lds[2][(64 + 32) * 72];
  const int tid = threadIdx.x, lane = tid & 63, wv = tid >> 6;
  const int r0 = blockIdx.y * 64, n0 = blockIdx.x * 32;
  const int arow = tid >> 3, acs = (tid & 7) * 8;
  f4v acc[2] = {};
  f8v raf[2]; s8v rb;
  auto issue = [&](int k0) {
#pragma unroll
    for (int it = 0; it < 2; ++it) {
      int r = r0 + arow + it * 32;
      int bq = r & 255, tq = r >> 8;
      raf[it] = *(const f8v*)(obs + ((size_t)bq * 64 + tq) * 1024 + k0 + acs);
    }
    rb = *(const s8v*)(Wobs_t + (n0 + arow) * 1024 + k0 + acs);
  };
  auto store = [&](short* buf) {
#pragma unroll
    for (int it = 0; it < 2; ++it) {
      s8v v;
#pragma unroll
      for (int j = 0; j < 8; ++j) v[j] = (short)f2bf(raf[it][j]);
      *(s8v*)&buf[(arow + it * 32) * 72 + acs] = v;
    }
    *(s8v*)&buf[(64 + arow) * 72 + acs] = rb;
  };
  auto compute = [&](const short* base) {
    const short* A_l = base; const short* B_l = base + 64 * 72;
    const int qa = (lane >> 4) * 8;
#pragma unroll
    for (int kk = 0; kk < 64; kk += 32) {
      bf8v af = *(const bf8v*)&A_l[(wv * 16 + (lane & 15)) * 72 + kk + qa];
#pragma unroll
      for (int ni = 0; ni < 2; ni++) {
        bf8v bf = *(const bf8v*)&B_l[(ni * 16 + (lane & 15)) * 72 + kk + qa];
        acc[ni] = mfma16(af, bf, acc[ni]);
      }
    }
  };
  issue(0); store(lds[0]); __syncthreads();
  for (int k0 = 0; k0 < 1024; k0 += 128) {
    issue(k0 + 64);
    compute(lds[0]);
    store(lds[1]);
    __syncthreads();
    if (k0 + 128 < 1024) issue(k0 + 128);
    compute(lds[1]);
    if (k0 + 128 < 1024) store(lds[0]);
    __syncthreads();
  }
  const int mrow = r0 + wv * 16 + (lane >> 4) * 4;
#pragma unroll
  for (int ni = 0; ni < 2; ni++) {
    int n = n0 + ni * 16 + (lane & 15);
    float bias = b_post_in[n];
#pragma unroll
    for (int r = 0; r < 4; r++)
      Oc[(size_t)(mrow + r) * 1024 + n] = f2bf(acc[ni][r] + bias);
  }
}

// ---------------- S1: rnn_in = relu([z|a_prev] @ W_rnn + b) (unchanged) ----------------
__global__ __launch_bounds__(256) void k_s1(
    const unsigned short* __restrict__ Zb, const unsigned short* __restrict__ a_t,
    const unsigned short* __restrict__ Wrnn_t, const float* __restrict__ b_rnn,
    unsigned short* __restrict__ X) {
  __shared__ __align__(16) short lds[(64 + 64) * 72];
  const int tid = threadIdx.x, lane = tid & 63, wv = tid >> 6;
  const int m0 = blockIdx.y * 64, n0 = blockIdx.x * 64;
  f4v acc[4] = {};
  short* A_l = lds;
  short* B_l = lds + 64 * 72;
  for (int k0 = 0; k0 < 320; k0 += 64) {
    __syncthreads();
    for (int it = 0; it < 2; ++it) {
      int idx = tid + it * 256, row = idx >> 3, cs = (idx & 7) * 8;
      int k = k0 + cs;
      const unsigned short* src = (k < 256) ? (Zb + (m0 + row) * 256 + k)
                                            : (a_t + (m0 + row) * 64 + (k - 256));
      *(s8v*)&A_l[row * 72 + cs] = *(const s8v*)src;
    }
    for (int it = 0; it < 2; ++it) {
      int idx = tid + it * 256, row = idx >> 3, cs = (idx & 7) * 8;
      *(s8v*)&B_l[row * 72 + cs] = *(const s8v*)(Wrnn_t + (n0 + row) * 320 + k0 + cs);
    }
    __syncthreads();
    const int qa = (lane >> 4) * 8;
#pragma unroll
    for (int kk = 0; kk < 64; kk += 32) {
      bf8v af = *(const bf8v*)&A_l[(wv * 16 + (lane & 15)) * 72 + kk + qa];
#pragma unroll
      for (int ni = 0; ni < 4; ni++) {
        bf8v bf = *(const bf8v*)&B_l[(ni * 16 + (lane & 15)) * 72 + kk + qa];
        acc[ni] = mfma16(af, bf, acc[ni]);
      }
    }
  }
  const int mrow = m0 + wv * 16 + (lane >> 4) * 4;
#pragma unroll
  for (int ni = 0; ni < 4; ni++) {
    int gn = n0 + ni * 16 + (lane & 15);
    float bias = b_rnn[gn];
#pragma unroll
    for (int r = 0; r < 4; r++) {
      float v = acc[ni][r] + bias;
      X[(mrow + r) * 3072 + gn] = f2bf(v > 0.0f ? v : 0.0f);
    }
  }
}

// ---------------- S2: fused GRU gates + h (double-buffered prefetch) ----------------
__global__ __launch_bounds__(256) void k_s2(
    const unsigned short* __restrict__ X,
    const unsigned short* __restrict__ Wih, const unsigned short* __restrict__ Whh,
    const float* __restrict__ bih, const float* __restrict__ bhh,
    const float* __restrict__ h_prev, int t0flag,
    float* __restrict__ h_out, unsigned short* __restrict__ Xh,
    unsigned short* __restrict__ Hb_t) {
  __shared__ __align__(16) short lds[2][(64 + 96) * 72];
  const int tid = threadIdx.x, lane = tid & 63, wv = tid >> 6;
  const int m0 = blockIdx.y * 64, d0 = blockIdx.x * 32;
  const int arow = tid >> 3, acs = (tid & 7) * 8;
  f4v acc[4][2] = {};  // r, u, new_i, new_h
  s8v ra[2], rb[3];
  auto issue = [&](int k0) {
#pragma unroll
    for (int it = 0; it < 2; ++it)
      ra[it] = *(const s8v*)(X + (m0 + arow + it * 32) * 3072 + k0 + acs);
    const bool ih = (k0 < 1024);
    const unsigned short* Wsrc = ih ? Wih : Whh;
    const int pitch = ih ? 1024 : 2048;
    const int kk0 = ih ? k0 : (k0 - 1024);
#pragma unroll
    for (int g = 0; g < 3; ++g)
      rb[g] = *(const s8v*)(Wsrc + (size_t)(g * 2048 + d0 + arow) * pitch + kk0 + acs);
  };
  auto store = [&](short* buf) {
#pragma unroll
    for (int it = 0; it < 2; ++it)
      *(s8v*)&buf[(arow + it * 32) * 72 + acs] = ra[it];
#pragma unroll
    for (int g = 0; g < 3; ++g)
      *(s8v*)&buf[(64 + g * 32 + arow) * 72 + acs] = rb[g];
  };
  auto compute = [&](const short* base, bool ih) {
    const short* A_l = base; const short* B_l = base + 64 * 72;
    const int qa = (lane >> 4) * 8;
#pragma unroll
    for (int kk = 0; kk < 64; kk += 32) {
      bf8v af = *(const bf8v*)&A_l[(wv * 16 + (lane & 15)) * 72 + kk + qa];
#pragma unroll
      for (int ni = 0; ni < 2; ni++) {
        bf8v b0 = *(const bf8v*)&B_l[(0 * 32 + ni * 16 + (lane & 15)) * 72 + kk + qa];
        bf8v b1 = *(const bf8v*)&B_l[(1 * 32 + ni * 16 + (lane & 15)) * 72 + kk + qa];
        bf8v b2 = *(const bf8v*)&B_l[(2 * 32 + ni * 16 + (lane & 15)) * 72 + kk + qa];
        acc[0][ni] = mfma16(af, b0, acc[0][ni]);
        acc[1][ni] = mfma16(af, b1, acc[1][ni]);
        if (ih) acc[2][ni] = mfma16(af, b2, acc[2][ni]);
        else    acc[3][ni] = mfma16(af, b2, acc[3][ni]);
      }
    }
  };
  issue(0); store(lds[0]); __syncthreads();
  for (int k0 = 0; k0 < 3072; k0 += 128) {
    issue(k0 + 64);
    compute(lds[0], k0 < 1024);
    store(lds[1]);
    __syncthreads();
    if (k0 + 128 < 3072) issue(k0 + 128);
    compute(lds[1], (k0 + 64) < 1024);
    if (k0 + 128 < 3072) store(lds[0]);
    __syncthreads();
  }
  const int mrow = m0 + wv * 16 + (lane >> 4) * 4;
#pragma unroll
  for (int ni = 0; ni < 2; ni++) {
    int d = d0 + ni * 16 + (lane & 15);
    float br = bih[d] + bhh[d];
    float bu = bih[2048 + d] + bhh[2048 + d];
    float bi = bih[4096 + d];
    float bh = bhh[4096 + d];
#pragma unroll
    for (int r = 0; r < 4; r++) {
      int m = mrow + r;
      float rg = sigm(acc[0][ni][r] + br);
      float ug = sigm(acc[1][ni][r] + bu);
      float ng = tanhf(acc[2][ni][r] + bi + rg * (acc[3][ni][r] + bh));
      float hp = t0flag ? 0.0f : h_prev[m * (Tc * DETc) + d];
      float h = (1.0f - ug) * ng + ug * hp;
      h_out[m * (Tc * DETc) + d] = h;
      unsigned short hb = f2bf(h);
      Xh[m * 3072 + d] = hb;
      Hb_t[m * 2048 + d] = hb;
    }
  }
}

// ---------------- S4': pf = relu(h @ Wpost_h + Oc[t]) (posterior only) ----------------
__global__ __launch_bounds__(256) void k_s4(
    const unsigned short* __restrict__ Xh, const unsigned short* __restrict__ Oc_t,
    const unsigned short* __restrict__ Wph_t,
    unsigned short* __restrict__ X3) {
  __shared__ __align__(16) short lds[2][(64 + 32) * 72];
  const int tid = threadIdx.x, lane = tid & 63, wv = tid >> 6;
  const int m0 = blockIdx.y * 64, n0 = blockIdx.x * 32;
  const int arow = tid >> 3, acs = (tid & 7) * 8;
  f4v acc[2] = {};
  s8v ra[2], rb;
  auto issue = [&](int k0) {
#pragma unroll
    for (int it = 0; it < 2; ++it)
      ra[it] = *(const s8v*)(Xh + (m0 + arow + it * 32) * 3072 + k0 + acs);
    rb = *(const s8v*)(Wph_t + (n0 + arow) * 2048 + k0 + acs);
  };
  auto store = [&](short* buf) {
#pragma unroll
    for (int it = 0; it < 2; ++it)
      *(s8v*)&buf[(arow + it * 32) * 72 + acs] = ra[it];
    *(s8v*)&buf[(64 + arow) * 72 + acs] = rb;
  };
  auto compute = [&](const short* base) {
    const short* A_l = base; const short* B_l = base + 64 * 72;
    const int qa = (lane >> 4) * 8;
#pragma unroll
    for (int kk = 0; kk < 64; kk += 32) {
      bf8v af = *(const bf8v*)&A_l[(wv * 16 + (lane & 15)) * 72 + kk + qa];
#pragma unroll
      for (int ni = 0; ni < 2; ni++) {
        bf8v bf = *(const bf8v*)&B_l[(ni * 16 + (lane & 15)) * 72 + kk + qa];
        acc[ni] = mfma16(af, bf, acc[ni]);
      }
    }
  };
  issue(0); store(lds[0]); __syncthreads();
  for (int k0 = 0; k0 < 2048; k0 += 128) {
    issue(k0 + 64);
    compute(lds[0]);
    store(lds[1]);
    __syncthreads();
    if (k0 + 128 < 2048) issue(k0 + 128);
    compute(lds[1]);
    if (k0 + 128 < 2048) store(lds[0]);
    __syncthreads();
  }
  const int mrow = m0 + wv * 16 + (lane >> 4) * 4;
#pragma unroll
  for (int ni = 0; ni < 2; ni++) {
    int n = n0 + ni * 16 + (lane & 15);
#pragma unroll
    for (int r = 0; r < 4; r++) {
      float v = acc[ni][r] + bf2f(Oc_t[(mrow + r) * 1024 + n]);
      X3[(mrow + r) * 1024 + n] = f2bf(v > 0.0f ? v : 0.0f);
    }
  }
}

// ---------------- S5': pm/ps + rsample (posterior only) ----------------
__global__ __launch_bounds__(256) void k_s5(
    const unsigned short* __restrict__ X3, const unsigned short* __restrict__ Wms_p,
    const float* __restrict__ b_post_ms, const float* __restrict__ noise_t,
    float* __restrict__ out_z, float* __restrict__ out_pm, float* __restrict__ out_ps,
    unsigned short* __restrict__ Zb) {
  __shared__ __align__(16) short lds[2][(64 + 32) * 72];
  const int tid = threadIdx.x, lane = tid & 63, wv = tid >> 6;
  const int m0 = blockIdx.y * 64, j0 = blockIdx.x * 16;
  const int arow = tid >> 3, acs = (tid & 7) * 8;
  f4v acc[2] = {};  // pm, pls
  s8v ra[2], rb;
  auto issue = [&](int k0) {
#pragma unroll
    for (int it = 0; it < 2; ++it)
      ra[it] = *(const s8v*)(X3 + (m0 + arow + it * 32) * 1024 + k0 + acs);
    int brow = (arow < 16) ? (j0 + arow) : (256 + j0 + arow - 16);
    rb = *(const s8v*)(Wms_p + brow * 1024 + k0 + acs);
  };
  auto store = [&](short* buf) {
#pragma unroll
    for (int it = 0; it < 2; ++it)
      *(s8v*)&buf[(arow + it * 32) * 72 + acs] = ra[it];
    *(s8v*)&buf[(64 + arow) * 72 + acs] = rb;
  };
  auto compute = [&](const short* base) {
    const short* A_l = base; const short* B_l = base + 64 * 72;
    const int qa = (lane >> 4) * 8;
#pragma unroll
    for (int kk = 0; kk < 64; kk += 32) {
      bf8v af = *(const bf8v*)&A_l[(wv * 16 + (lane & 15)) * 72 + kk + qa];
      bf8v bp = *(const bf8v*)&B_l[((lane & 15)) * 72 + kk + qa];
      bf8v bl = *(const bf8v*)&B_l[(16 + (lane & 15)) * 72 + kk + qa];
      acc[0] = mfma16(af, bp, acc[0]);
      acc[1] = mfma16(af, bl, acc[1]);
    }
  };
  issue(0); store(lds[0]); __syncthreads();
  for (int k0 = 0; k0 < 1024; k0 += 128) {
    issue(k0 + 64);
    compute(lds[0]);
    store(lds[1]);
    __syncthreads();
    if (k0 + 128 < 1024) issue(k0 + 128);
    compute(lds[1]);
    if (k0 + 128 < 1024) store(lds[0]);
    __syncthreads();
  }
  const int mrow = m0 + wv * 16 + (lane >> 4) * 4;
  const int j = j0 + (lane & 15);
  const float bpm = b_post_ms[j], bpl = b_post_ms[256 + j];
#pragma unroll
  for (int r = 0; r < 4; r++) {
    int m = mrow + r;
    float pm = acc[0][r] + bpm;
    float ps = softplusf(acc[1][r] + bpl) + 0.1f;
    float z = pm + ps * noise_t[m * (Tc * STOc) + j];
    int o = m * (Tc * STOc) + j;
    out_pm[o] = pm; out_ps[o] = ps; out_z[o] = z;
    Zb[m * 256 + j] = f2bf(z);
  }
}

// ---------------- post-loop: rf = relu(Hb @ Wprior + b) ----------------
__global__ __launch_bounds__(256) void k_pri1(
    const unsigned short* __restrict__ Hb, const unsigned short* __restrict__ Wpri_t,
    const float* __restrict__ b_prior_in, unsigned short* __restrict__ rfb) {
  __shared__ __align__(16) short lds[2][(64 + 32) * 72];
  const int tid = threadIdx.x, lane = tid & 63, wv = tid >> 6;
  const int r0 = blockIdx.y * 64, n0 = blockIdx.x * 32;
  const int arow = tid >> 3, acs = (tid & 7) * 8;
  f4v acc[2] = {};
  s8v ra[2], rb;
  auto issue = [&](int k0) {
#pragma unroll
    for (int it = 0; it < 2; ++it)
      ra[it] = *(const s8v*)(Hb + (size_t)(r0 + arow + it * 32) * 2048 + k0 + acs);
    rb = *(const s8v*)(Wpri_t + (n0 + arow) * 2048 + k0 + acs);
  };
  auto store = [&](short* buf) {
#pragma unroll
    for (int it = 0; it < 2; ++it)
      *(s8v*)&buf[(arow + it * 32) * 72 + acs] = ra[it];
    *(s8v*)&buf[(64 + arow) * 72 + acs] = rb;
  };
  auto compute = [&](const short* base) {
    const short* A_l = base; const short* B_l = base + 64 * 72;
    const int qa = (lane >> 4) * 8;
#pragma unroll
    for (int kk = 0; kk < 64; kk += 32) {
      bf8v af = *(const bf8v*)&A_l[(wv * 16 + (lane & 15)) * 72 + kk + qa];
#pragma unroll
      for (int ni = 0; ni < 2; ni++) {
        bf8v bf = *(const bf8v*)&B_l[(ni * 16 + (lane & 15)) * 72 + kk + qa];
        acc[ni] = mfma16(af, bf, acc[ni]);
      }
    }
  };
  issue(0); store(lds[0]); __syncthreads();
  for (int k0 = 0; k0 < 2048; k0 += 128) {
    issue(k0 + 64);
    compute(lds[0]);
    store(lds[1]);
    __syncthreads();
    if (k0 + 128 < 2048) issue(k0 + 128);
    compute(lds[1]);
    if (k0 + 128 < 2048) store(lds[0]);
    __syncthreads();
  }
  const int mrow = r0 + wv * 16 + (lane >> 4) * 4;
#pragma unroll
  for (int ni = 0; ni < 2; ni++) {
    int n = n0 + ni * 16 + (lane & 15);
    float bias = b_prior_in[n];
#pragma unroll
    for (int r = 0; r < 4; r++) {
      float v = acc[ni][r] + bias;
      rfb[(size_t)(mrow + r) * 1024 + n] = f2bf(v > 0.0f ? v : 0.0f);
    }
  }
}

// ---------------- post-loop: qm/qs = rf @ Wms_q + b (softplus on qls) ----------------
__global__ __launch_bounds__(256) void k_pri2(
    const unsigned short* __restrict__ rfb, const unsigned short* __restrict__ Wms_q,
    const float* __restrict__ b_prior_ms,
    float* __restrict__ out_qm, float* __restrict__ out_qs) {
  __shared__ __align__(16) short lds[2][(64 + 32) * 72];
  const int tid = threadIdx.x, lane = tid & 63, wv = tid >> 6;
  const int r0 = blockIdx.y * 64, n0 = blockIdx.x * 32;
  const int arow = tid >> 3, acs = (tid & 7) * 8;
  f4v acc[2] = {};
  s8v ra[2], rb;
  auto issue = [&](int k0) {
#pragma unroll
    for (int it = 0; it < 2; ++it)
      ra[it] = *(const s8v*)(rfb + (size_t)(r0 + arow + it * 32) * 1024 + k0 + acs);
    rb = *(const s8v*)(Wms_q + (n0 + arow) * 1024 + k0 + acs);
  };
  auto store = [&](short* buf) {
#pragma unroll
    for (int it = 0; it < 2; ++it)
      *(s8v*)&buf[(arow + it * 32) * 72 + acs] = ra[it];
    *(s8v*)&buf[(64 + arow) * 72 + acs] = rb;
  };
  auto compute = [&](const short* base) {
    const short* A_l = base; const short* B_l = base + 64 * 72;
    const int qa = (lane >> 4) * 8;
#pragma unroll
    for (int kk = 0; kk < 64; kk += 32) {
      bf8v af = *(const bf8v*)&A_l[(wv * 16 + (lane & 15)) * 72 + kk + qa];
#pragma unroll
      for (int ni = 0; ni < 2; ni++) {
        bf8v bf = *(const bf8v*)&B_l[(ni * 16 + (lane & 15)) * 72 + kk + qa];
        acc[ni] = mfma16(af, bf, acc[ni]);
      }
    }
  };
  issue(0); store(lds[0]); __syncthreads();
  for (int k0 = 0; k0 < 1024; k0 += 128) {
    issue(k0 + 64);
    compute(lds[0]);
    store(lds[1]);
    __syncthreads();
    if (k0 + 128 < 1024) issue(k0 + 128);
    compute(lds[1]);
    if (k0 + 128 < 1024) store(lds[0]);
    __syncthreads();
  }
  const int mrow = r0 + wv * 16 + (lane >> 4) * 4;
#pragma unroll
  for (int ni = 0; ni < 2; ni++) {
    int n = n0 + ni * 16 + (lane & 15);
    float bias = b_prior_ms[n];
#pragma unroll
    for (int r = 0; r < 4; r++) {
      int m = mrow + r;
      int bq = m & 255, tq = m >> 8;
      size_t base_o = ((size_t)bq * 64 + tq) * 256;
      float v = acc[ni][r] + bias;
      if (n < 256) out_qm[base_o + n] = v;
      else         out_qs[base_o + (n - 256)] = softplusf(v) + 0.1f;
    }
  }
}

// ---------------- host ----------------
extern "C" void kernel_launch(void* const* d_in, const int* in_sizes, int n_in,
                              void* d_out, int out_size, void* d_ws, size_t ws_size,
                              hipStream_t stream) {
  const float* obs      = (const float*)d_in[0];
  const float* actions  = (const float*)d_in[1];
  const float* noise    = (const float*)d_in[4];
  const float* W_rnn    = (const float*)d_in[5];
  const float* b_rnn    = (const float*)d_in[6];
  const float* Wih      = (const float*)d_in[7];
  const float* Whh      = (const float*)d_in[8];
  const float* bih      = (const float*)d_in[9];
  const float* bhh      = (const float*)d_in[10];
  const float* Wpost_in = (const float*)d_in[11];
  const float* b_post_in= (const float*)d_in[12];
  const float* Wpost_ms = (const float*)d_in[13];
  const float* b_post_ms= (const float*)d_in[14];
  const float* Wprior_in= (const float*)d_in[15];
  const float* b_prior_in=(const float*)d_in[16];
  const float* Wprior_ms= (const float*)d_in[17];
  const float* b_prior_ms=(const float*)d_in[18];

  float* out    = (float*)d_out;
  float* out_h  = out;
  float* out_z  = out_h  + (size_t)Bc * Tc * DETc;
  float* out_pm = out_z  + (size_t)Bc * Tc * STOc;
  float* out_ps = out_pm + (size_t)Bc * Tc * STOc;
  float* out_qm = out_ps + (size_t)Bc * Tc * STOc;
  float* out_qs = out_qm + (size_t)Bc * Tc * STOc;

  char* w = (char*)d_ws;
  auto alloc = [&](size_t bytes) -> char* {
    char* p = w; w += (bytes + 255) & ~(size_t)255; return p;
  };
  unsigned short* Wih_b   = (unsigned short*)alloc((size_t)6144 * 1024 * 2);
  unsigned short* Whh_b   = (unsigned short*)alloc((size_t)6144 * 2048 * 2);
  unsigned short* Wrnn_t  = (unsigned short*)alloc((size_t)1024 * 320 * 2);
  unsigned short* Wph_t   = (unsigned short*)alloc((size_t)1024 * 2048 * 2);
  unsigned short* Wobs_t  = (unsigned short*)alloc((size_t)1024 * 1024 * 2);
  unsigned short* Wpri_t  = (unsigned short*)alloc((size_t)1024 * 2048 * 2);
  unsigned short* Wms_p   = (unsigned short*)alloc((size_t)512 * 1024 * 2);
  unsigned short* Wms_q   = (unsigned short*)alloc((size_t)512 * 1024 * 2);
  unsigned short* a_shift = (unsigned short*)alloc((size_t)Tc * Bc * Ac * 2);
  unsigned short* Oc      = (unsigned short*)alloc((size_t)16384 * 1024 * 2); // reused as rfb post-loop
  unsigned short* Hb      = (unsigned short*)alloc((size_t)16384 * 2048 * 2);
  unsigned short* Xbuf    = (unsigned short*)alloc((size_t)256 * 3072 * 2);
  unsigned short* Zb      = (unsigned short*)alloc((size_t)256 * 256 * 2);
  unsigned short* X3      = (unsigned short*)alloc((size_t)256 * 1024 * 2);
  unsigned short* rfb     = Oc;  // Oc dead after loop; alias to save workspace

  // weight conversion / layout builds (re-done every call: ws is re-poisoned)
  k_cvt<<<(6144 * 1024 + 255) / 256, 256, 0, stream>>>(Wih, Wih_b, 6144 * 1024);
  k_cvt<<<(6144 * 2048 + 255) / 256, 256, 0, stream>>>(Whh, Whh_b, 6144 * 2048);
  k_tr<<<dim3(20, 64),  256, 0, stream>>>(W_rnn, 1024, Wrnn_t, 320, 1024, 320);
  k_tr<<<dim3(128, 64), 256, 0, stream>>>(Wpost_in, 1024, Wph_t, 2048, 1024, 2048);
  k_tr<<<dim3(64, 64),  256, 0, stream>>>(Wpost_in + (size_t)2048 * 1024, 1024, Wobs_t, 1024, 1024, 1024);
  k_tr<<<dim3(128, 64), 256, 0, stream>>>(Wprior_in, 1024, Wpri_t, 2048, 1024, 2048);
  k_tr<<<dim3(64, 32),  256, 0, stream>>>(Wpost_ms, 512, Wms_p, 1024, 512, 1024);
  k_tr<<<dim3(64, 32),  256, 0, stream>>>(Wprior_ms, 512, Wms_q, 1024, 512, 1024);
  k_ashift<<<(Tc * Bc * Ac + 255) / 256, 256, 0, stream>>>(actions, a_shift);
  k_zero16<<<(256 * 3072 + 255) / 256, 256, 0, stream>>>(Xbuf, 256 * 3072);
  k_zero16<<<(256 * 256 + 255) / 256, 256, 0, stream>>>(Zb, 256 * 256);

  // hoisted obs contribution: Oc[t*256+b][n] = obs[b][t] @ Wobs + b_post_in
  k_obs<<<dim3(32, 256), 256, 0, stream>>>(obs, Wobs_t, b_post_in, Oc);

  for (int t = 0; t < Tc; ++t) {
    k_s1<<<dim3(16, 4), 256, 0, stream>>>(Zb, a_shift + (size_t)t * Bc * Ac, Wrnn_t, b_rnn, Xbuf);
    k_s2<<<dim3(64, 4), 256, 0, stream>>>(Xbuf, Wih_b, Whh_b, bih, bhh,
        (t == 0) ? out_h : (out_h + (size_t)(t - 1) * DETc), (t == 0) ? 1 : 0,
        out_h + (size_t)t * DETc, Xbuf + 1024, Hb + (size_t)t * 256 * 2048);
    k_s4<<<dim3(32, 4), 256, 0, stream>>>(Xbuf + 1024, Oc + (size_t)t * 256 * 1024,
        Wph_t, X3);
    k_s5<<<dim3(16, 4), 256, 0, stream>>>(X3, Wms_p, b_post_ms,
        noise + (size_t)t * STOc,
        out_z + (size_t)t * STOc, out_pm + (size_t)t * STOc, out_ps + (size_t)t * STOc, Zb);
  }

  // hoisted prior path over all 16384 rows
  k_pri1<<<dim3(32, 256), 256, 0, stream>>>(Hb, Wpri_t, b_prior_in, rfb);
  k_pri2<<<dim3(16, 256), 256, 0, stream>>>(rfb, Wms_q, b_prior_ms, out_qm, out_qs);
}